// Round 13
// baseline (1269.642 us; speedup 1.0000x reference)
//
#include <hip/hip_runtime.h>
#include <stdint.h>

#define NP 2048
#define KNN 40
#define CAP 256          // candidate buffer per row (16-bit threshold is coarse)

__device__ __forceinline__ unsigned fOrd(float f) {
    unsigned u = __float_as_uint(f);
    return u ^ ((unsigned)((int)u >> 31) | 0x80000000u);
}
__device__ __forceinline__ unsigned long long dOrd(double d) {
    unsigned long long u = (unsigned long long)__double_as_longlong(d);
    return u ^ (((unsigned long long)((long long)u >> 63)) | 0x8000000000000000ull);
}

// ---------------------------------------------------------------------------
// prep: per point: xx = sum x^2 (fp32), p[o] = Wd[o,:]·x, r[o] = (Wc-Wd)[o,:]·x,
// XT[b][n][0..CP) = x (point-contiguous, zero-padded) + fp64 norm at offset CP
// (sequential c-order — must match refine's usage).
// ---------------------------------------------------------------------------
template<int C, int CP, int CPX>
__global__ void prep_kernel(const float* __restrict__ X, long bstride,
                            const float* __restrict__ W,
                            float* __restrict__ p, float* __restrict__ r,
                            float* __restrict__ xx, float* __restrict__ XT) {
    __shared__ float wdT[C][32];
    __shared__ float wrT[C][32];
    int tid = threadIdx.x;
    for (int i = tid; i < 32 * C; i += 256) {
        int o = i / C, c = i - o * C;
        float wd = W[o * 2 * C + c];
        float wc = W[o * 2 * C + C + c];
        wdT[c][o] = wd;
        wrT[c][o] = wc - wd;
    }
    __syncthreads();
    int lane = tid & 63;
    int o = lane & 31;
    int h = lane >> 5;
    int wv = tid >> 6;
    int flat = blockIdx.x * 8 + wv * 2 + h;   // 2048 wgs * 8 points = B*N
    int b = flat >> 11, n = flat & 2047;
    const float* Xb = X + (long)b * bstride + n;
    float pacc = 0.f, racc = 0.f, xxa = 0.f, xto = 0.f;
    double xxd = 0.0;
#pragma unroll
    for (int c = 0; c < C; c++) {
        float xv = Xb[(long)c * NP];
        pacc = fmaf(wdT[c][o], xv, pacc);
        racc = fmaf(wrT[c][o], xv, racc);
        xxa += xv * xv;
        xxd += (double)xv * (double)xv;       // sequential c order (refine-consistent)
        if (c == o) xto = xv;
    }
    long base = ((long)b * NP + n) * 32 + o;
    p[base] = pacc;
    r[base] = racc;
    long rowb = ((long)b * NP + n) * CPX;
    if (o < CP) XT[rowb + o] = (o < C) ? xto : 0.f;
    if (o == 0) {
        xx[b * NP + n] = xxa;
        *reinterpret_cast<double*>(&XT[rowb + CP]) = xxd;
    }
}

// ---------------------------------------------------------------------------
// knn: per (b,n) row. Design rules (R2-R12, measured):
//  (1) register ARRAYS well under ~95 (compiler caps at 128 VGPR);
//      wave-uniform queries in LDS broadcast, keys 16-bit packed.
//  (2) pass-1 is LDS-instruction-bound -> amortize tile reads over 4 ROWS
//      per wave (R10 tile geometry, proven): per c, one b32 pair (xv0/xv1)
//      + one b128 query broadcast serve 8 fma = 0.25 LDS instr/distance.
//  (3) R7/R11 source structures retired (4/4 container faults each); this
//      keeps R10's exact staging + tile read pattern.
//  select: 16-iter ballot bisection on 16-bit keys -> rank-40 bucket;
//  candidates {k16 <= rank40+2}; refine in float64 from point-contiguous XT;
//  64-bit bisect -> exact top-40; boundary ties lowest-index-first via
//  m-bisect. Defensive sel-init + index masking retained.
// wg = 256 = 4 waves; each wave owns 4 rows; 1024 wgs (128 per batch).
// ---------------------------------------------------------------------------
template<int C, int CP, int CPX>
__global__ __launch_bounds__(256, 2)
void knn_kernel(const float* __restrict__ X, long bstride,
                const float* __restrict__ p, const float* __restrict__ r,
                const float* __restrict__ xx, const float* __restrict__ XT,
                float* __restrict__ mmax, float* __restrict__ mmin,
                float* __restrict__ sums) {
    __shared__ __align__(16) float xt[C * 128];   // [c][m] tile, m contiguous (R10-proven)
    __shared__ float xxt[128];
    __shared__ __align__(16) float qld[4][CP][4]; // [wave][c][row 0..3]
    __shared__ unsigned short sel[16][KNN];
    __shared__ unsigned short cand[16][CAP];
    __shared__ float S1loc[32], S2loc[32];
    int tid = threadIdx.x;
    if (tid < 32) { S1loc[tid] = 0.f; S2loc[tid] = 0.f; }
    for (int i = tid; i < (16 * KNN) / 2; i += 256) ((int*)sel)[i] = 0;  // defensive init
    int lane = tid & 63;
    int wv = tid >> 6;
    int b = blockIdx.x >> 7;              // 128 wgs per batch
    int n0 = (blockIdx.x & 127) * 16;
    int nbase = n0 + wv * 4;              // this wave's 4 rows
    const float* Xb = X + (long)b * bstride;
    const float* XTb = XT + (long)b * NP * CPX;
    long bNP = (long)b * NP;

    // queries -> LDS (wave-private rows; wave-coherent, no barrier needed)
    if (lane < CP) {
#pragma unroll
        for (int rr = 0; rr < 4; rr++)
            qld[wv][lane][rr] = XTb[(long)(nbase + rr) * CPX + lane];
    }
    float xxn0 = xx[bNP + nbase + 0];
    float xxn1 = xx[bNP + nbase + 1];
    float xxn2 = xx[bNP + nbase + 2];
    float xxn3 = xx[bNP + nbase + 3];

    unsigned u0[16], u1[16], u2[16], u3[16];  // packed 16-bit keys, 2 per reg
#pragma unroll
    for (int t = 0; t < 16; t++) {
        __syncthreads();
        // stage tile: float4 global load -> b128 LDS write, stride-1 (R10-proven)
        for (int i = tid; i < C * 32; i += 256) {
            int c = i >> 5, g = i & 31;
            *(float4*)&xt[c * 128 + g * 4] = *(const float4*)&Xb[(long)c * NP + t * 128 + g * 4];
        }
        if (tid < 128) xxt[tid] = xx[bNP + t * 128 + tid];
        __syncthreads();
        float a00 = 0.f, a01 = 0.f, a10 = 0.f, a11 = 0.f;
        float a20 = 0.f, a21 = 0.f, a30 = 0.f, a31 = 0.f;
#pragma unroll
        for (int c = 0; c < C; c++) {
            float4 q = *(const float4*)&qld[wv][c][0];   // b128 broadcast (4 rows)
            float xv0 = xt[c * 128 + lane];              // b32 pair, conflict-free
            float xv1 = xt[c * 128 + 64 + lane];
            a00 = fmaf(q.x, xv0, a00); a01 = fmaf(q.x, xv1, a01);
            a10 = fmaf(q.y, xv0, a10); a11 = fmaf(q.y, xv1, a11);
            a20 = fmaf(q.z, xv0, a20); a21 = fmaf(q.z, xv1, a21);
            a30 = fmaf(q.w, xv0, a30); a31 = fmaf(q.w, xv1, a31);
        }
        float xxm0 = xxt[lane];
        float xxm1 = xxt[64 + lane];
        u0[t] = ((fOrd((xxn0 - 2.0f * a01) + xxm1) >> 16) << 16) | (fOrd((xxn0 - 2.0f * a00) + xxm0) >> 16);
        u1[t] = ((fOrd((xxn1 - 2.0f * a11) + xxm1) >> 16) << 16) | (fOrd((xxn1 - 2.0f * a10) + xxm0) >> 16);
        u2[t] = ((fOrd((xxn2 - 2.0f * a21) + xxm1) >> 16) << 16) | (fOrd((xxn2 - 2.0f * a20) + xxm0) >> 16);
        u3[t] = ((fOrd((xxn3 - 2.0f * a31) + xxm1) >> 16) << 16) | (fOrd((xxn3 - 2.0f * a30) + xxm0) >> 16);
    }

    unsigned long long lmlt = (1ull << lane) - 1ull;
    auto do_row = [&](unsigned (&u)[16], int rsel, int row, int n) {
        // --- pass 1 select: rank-40 among 16-bit truncated keys ---
        unsigned lo = 0u, hi = 0xFFFFu;
        while (lo < hi) {
            unsigned mid = (lo + hi) >> 1;
            int cnt = 0;
#pragma unroll
            for (int t = 0; t < 16; t++) {
                cnt += __popcll(__ballot((u[t] & 0xFFFFu) <= mid));
                cnt += __popcll(__ballot((u[t] >> 16) <= mid));
            }
            if (cnt >= KNN) hi = mid; else lo = mid + 1;
        }
        unsigned thr = (lo > 0xFFFDu) ? 0xFFFFu : lo + 2;   // 2-bucket margin
        // --- candidate list (m = t*128 + hh*64 + lane) ---
        int base = 0;
#pragma unroll
        for (int t = 0; t < 16; t++) {
#pragma unroll
            for (int hh = 0; hh < 2; hh++) {
                unsigned k16 = hh ? (u[t] >> 16) : (u[t] & 0xFFFFu);
                bool pr = (k16 <= thr);
                unsigned long long mk = __ballot(pr);
                if (pr) {
                    int pos = base + __popcll(mk & lmlt);
                    if (pos < CAP) cand[row][pos] = (unsigned short)(t * 128 + hh * 64 + lane);
                }
                base += __popcll(mk);
            }
        }
        int cnt = base < CAP ? base : CAP;
        // --- refine candidates in float64 (query via LDS broadcast) ---
        double xxdn = *reinterpret_cast<const double*>(&XTb[(long)n * CPX + CP]);
        unsigned long long key[CAP / 64]; int midx[CAP / 64];
#pragma unroll
        for (int s3 = 0; s3 < CAP / 64; s3++) {
            int slot = s3 * 64 + lane;
            key[s3] = ~0ull; midx[s3] = 0;
            if (slot < cnt) {
                int m = cand[row][slot] & (NP - 1);   // defensive mask
                midx[s3] = m;
                const float* xmp = XTb + (long)m * CPX;
                double inner = 0.0;
#pragma unroll
                for (int g = 0; g < CP / 4; g++) {
                    float4 v = *(const float4*)&xmp[g * 4];
                    inner += (double)qld[wv][g * 4 + 0][rsel] * (double)v.x;
                    inner += (double)qld[wv][g * 4 + 1][rsel] * (double)v.y;
                    inner += (double)qld[wv][g * 4 + 2][rsel] * (double)v.z;
                    inner += (double)qld[wv][g * 4 + 3][rsel] * (double)v.w;
                }
                double xxm = *reinterpret_cast<const double*>(&xmp[CP]);
                double dd = (xxdn - 2.0 * inner) + xxm;
                key[s3] = dOrd(dd);
            }
        }
        // --- 64-bit bisect for rank-40 among candidates ---
        unsigned long long lo64 = 0ull, hi64 = ~0ull;
        while (lo64 < hi64) {
            unsigned long long mid = lo64 + ((hi64 - lo64) >> 1);
            int c2 = 0;
#pragma unroll
            for (int s3 = 0; s3 < CAP / 64; s3++)
                c2 += __popcll(__ballot(key[s3] <= mid));
            if (c2 >= KNN) hi64 = mid; else lo64 = mid + 1;
        }
        // --- emit strictly-smaller ---
        int b2 = 0;
#pragma unroll
        for (int s3 = 0; s3 < CAP / 64; s3++) {
            bool pr = (key[s3] < lo64);
            unsigned long long mk = __ballot(pr);
            if (pr) {
                int pos = b2 + __popcll(mk & lmlt);
                if (pos < KNN) sel[row][pos] = (unsigned short)midx[s3];
            }
            b2 += __popcll(mk);
        }
        // --- boundary ties: take the (KNN-b2) LOWEST m among tied keys ---
        {
            int need = KNN - b2;
            int mlo = 0, mhi = NP - 1;
            while (mlo < mhi) {
                int mm = (mlo + mhi) >> 1;
                int ct = 0;
#pragma unroll
                for (int s3 = 0; s3 < CAP / 64; s3++)
                    ct += __popcll(__ballot(key[s3] == lo64 && midx[s3] <= mm));
                if (ct >= need) mhi = mm; else mlo = mm + 1;
            }
#pragma unroll
            for (int s3 = 0; s3 < CAP / 64; s3++) {
                bool pr = (key[s3] == lo64 && midx[s3] <= mlo);
                unsigned long long mk = __ballot(pr);
                if (pr) {
                    int pos = b2 + __popcll(mk & lmlt);
                    if (pos < KNN) sel[row][pos] = (unsigned short)midx[s3];
                }
                b2 += __popcll(mk);
            }
        }
        // --- fused gather-reduce over the selected 40: lane = (o, half) ---
        int o = lane & 31, h = lane >> 5;
        float s1 = 0.f, s2 = 0.f;
        float mx = -__builtin_inff(), mn = __builtin_inff();
        const float* pb = p + bNP * 32 + o;
        for (int k = h * 20; k < h * 20 + 20; k++) {
            int m = sel[row][k] & (NP - 1);           // defensive mask
            float pv = pb[(long)m * 32];
            s1 += pv;
            s2 = fmaf(pv, pv, s2);
            mx = fmaxf(mx, pv);
            mn = fminf(mn, pv);
        }
        s1 += __shfl_xor(s1, 32);
        s2 += __shfl_xor(s2, 32);
        mx = fmaxf(mx, __shfl_xor(mx, 32));
        mn = fminf(mn, __shfl_xor(mn, 32));
        if (h == 0) {
            long bse = (bNP + n) * 32 + o;
            float q = r[bse];
            mmax[bse] = mx + q;
            mmin[bse] = mn + q;
            atomicAdd(&S1loc[o], s1 + 40.f * q);
            atomicAdd(&S2loc[o], fmaf(2.f * q, s1, fmaf(40.f * q, q, s2)));
        }
    };
    do_row(u0, 0, wv * 4 + 0, nbase + 0);
    do_row(u1, 1, wv * 4 + 1, nbase + 1);
    do_row(u2, 2, wv * 4 + 2, nbase + 2);
    do_row(u3, 3, wv * 4 + 3, nbase + 3);
    __syncthreads();
    if (tid < 32) {
        atomicAdd(&sums[tid], S1loc[tid]);
        atomicAdd(&sums[32 + tid], S2loc[tid]);
    }
}

// ---------------------------------------------------------------------------
// finish: per-channel BN affine from global sums, monotone max/min trick,
// LeakyReLU, residual, write slice of cat into d_out [B][128][N]
// ---------------------------------------------------------------------------
__global__ void finish_kernel(const float* __restrict__ mmax, const float* __restrict__ mmin,
                              const float* __restrict__ sums,
                              const float* __restrict__ g, const float* __restrict__ be,
                              const float* __restrict__ resid,
                              float* __restrict__ outb) {
    int id = blockIdx.x * 256 + threadIdx.x;     // B*32*N = 524288
    int b = id >> 16;
    int o = (id >> 11) & 31;
    int n = id & 2047;
    const float cntf = 655360.0f;                 // B*N*K
    float mean = sums[o] / cntf;
    float var = sums[32 + o] / cntf - mean * mean;
    float sc = g[o] / sqrtf(var + 1e-5f);
    float sh = be[o] - mean * sc;
    long bse = ((long)b * NP + n) * 32 + o;
    float v = (sc >= 0.f) ? mmax[bse] : mmin[bse];
    float y = sc * v + sh;
    y = (y >= 0.f) ? y : 0.2f * y;
    long ob = ((long)b * 128 + o) * NP + n;
    if (resid) y += resid[ob];
    outb[ob] = y;
}

// ---------------------------------------------------------------------------
// final in-place GEMM on d_out: out[b,o,n] = sum_c W5[o,c]*cat[b,c,n]
// ---------------------------------------------------------------------------
__global__ void final_gemm(const float* __restrict__ W5, float* __restrict__ out) {
    __shared__ __align__(16) float catL[128][32];
    int b = blockIdx.x >> 6;
    int n0 = (blockIdx.x & 63) * 32;
    int tid = threadIdx.x;
    for (int i = tid; i < 128 * 32; i += 256) {
        int c = i >> 5, nn = i & 31;
        catL[c][nn] = out[((long)b * 128 + c) * NP + n0 + nn];
    }
    __syncthreads();
    int og = tid >> 3, ng = tid & 7;
    int o0 = og * 4, nl = ng * 4;
    float acc[4][4] = {};
    for (int c = 0; c < 128; c++) {
        float4 cv = *(const float4*)&catL[c][nl];
#pragma unroll
        for (int i = 0; i < 4; i++) {
            float w = W5[(o0 + i) * 128 + c];
            acc[i][0] = fmaf(w, cv.x, acc[i][0]);
            acc[i][1] = fmaf(w, cv.y, acc[i][1]);
            acc[i][2] = fmaf(w, cv.z, acc[i][2]);
            acc[i][3] = fmaf(w, cv.w, acc[i][3]);
        }
    }
#pragma unroll
    for (int i = 0; i < 4; i++) {
        float4 vv = make_float4(acc[i][0], acc[i][1], acc[i][2], acc[i][3]);
        *(float4*)&out[((long)b * 128 + o0 + i) * NP + n0 + nl] = vv;
    }
}

extern "C" void kernel_launch(void* const* d_in, const int* in_sizes, int n_in,
                              void* d_out, int out_size, void* d_ws, size_t ws_size,
                              hipStream_t stream) {
    const float* x  = (const float*)d_in[0];
    const float* W1 = (const float*)d_in[1];
    const float* W2 = (const float*)d_in[2];
    const float* W3 = (const float*)d_in[3];
    const float* W4 = (const float*)d_in[4];
    const float* W5 = (const float*)d_in[5];
    const float* g1 = (const float*)d_in[6];
    const float* b1 = (const float*)d_in[7];
    const float* g2 = (const float*)d_in[8];
    const float* b2 = (const float*)d_in[9];
    const float* g3 = (const float*)d_in[10];
    const float* b3 = (const float*)d_in[11];
    const float* g4 = (const float*)d_in[12];
    const float* b4 = (const float*)d_in[13];
    float* out = (float*)d_out;
    float* ws  = (float*)d_ws;
    // ws layout (floats): p | r | mmax | mmin | xx | sums | XT
    float* p    = ws;
    float* r    = ws + 524288;
    float* mmax = ws + 1048576;
    float* mmin = ws + 1572864;
    float* xx   = ws + 2097152;
    float* sums = ws + 2113536;
    float* XT   = ws + 2113792;   // up to 8*2048*36 = 589824 floats
    hipMemsetAsync(sums, 0, 256 * sizeof(float), stream);

    // block 1 (C=9, CP=12, CPX=16)
    prep_kernel<9, 12, 16><<<2048, 256, 0, stream>>>(x, 9L * NP, W1, p, r, xx, XT);
    knn_kernel<9, 12, 16><<<1024, 256, 0, stream>>>(x, 9L * NP, p, r, xx, XT, mmax, mmin, sums);
    finish_kernel<<<2048, 256, 0, stream>>>(mmax, mmin, sums, g1, b1, nullptr, out);
    // block 2 (C=32, CP=32, CPX=36)
    const float* x1 = out;
    prep_kernel<32, 32, 36><<<2048, 256, 0, stream>>>(x1, 128L * NP, W2, p, r, xx, XT);
    knn_kernel<32, 32, 36><<<1024, 256, 0, stream>>>(x1, 128L * NP, p, r, xx, XT, mmax, mmin, sums + 64);
    finish_kernel<<<2048, 256, 0, stream>>>(mmax, mmin, sums + 64, g2, b2, x1, out + 32 * NP);
    // block 3
    const float* x2 = out + 32 * NP;
    prep_kernel<32, 32, 36><<<2048, 256, 0, stream>>>(x2, 128L * NP, W3, p, r, xx, XT);
    knn_kernel<32, 32, 36><<<1024, 256, 0, stream>>>(x2, 128L * NP, p, r, xx, XT, mmax, mmin, sums + 128);
    finish_kernel<<<2048, 256, 0, stream>>>(mmax, mmin, sums + 128, g3, b3, x2, out + 64 * NP);
    // block 4
    const float* x3 = out + 64 * NP;
    prep_kernel<32, 32, 36><<<2048, 256, 0, stream>>>(x3, 128L * NP, W4, p, r, xx, XT);
    knn_kernel<32, 32, 36><<<1024, 256, 0, stream>>>(x3, 128L * NP, p, r, xx, XT, mmax, mmin, sums + 192);
    finish_kernel<<<2048, 256, 0, stream>>>(mmax, mmin, sums + 192, g4, b4, x3, out + 96 * NP);

    final_gemm<<<512, 256, 0, stream>>>(W5, out);
}

// Round 14
// 875.585 us; speedup vs baseline: 1.4501x; 1.4501x over previous
//
#include <hip/hip_runtime.h>
#include <stdint.h>

#define NP 2048
#define KNN 40
#define CAP 256          // candidate buffer per row (16-bit threshold is coarse)

__device__ __forceinline__ unsigned fOrd(float f) {
    unsigned u = __float_as_uint(f);
    return u ^ ((unsigned)((int)u >> 31) | 0x80000000u);
}
__device__ __forceinline__ unsigned long long dOrd(double d) {
    unsigned long long u = (unsigned long long)__double_as_longlong(d);
    return u ^ (((unsigned long long)((long long)u >> 63)) | 0x8000000000000000ull);
}

// ---------------------------------------------------------------------------
// prep: per point: xx = sum x^2 (fp32), p[o] = Wd[o,:]·x, r[o] = (Wc-Wd)[o,:]·x,
// XT[b][n][0..CP) = x (point-contiguous, zero-padded) + fp64 norm at offset CP
// (sequential c-order — must match refine's usage).
// ---------------------------------------------------------------------------
template<int C, int CP, int CPX>
__global__ void prep_kernel(const float* __restrict__ X, long bstride,
                            const float* __restrict__ W,
                            float* __restrict__ p, float* __restrict__ r,
                            float* __restrict__ xx, float* __restrict__ XT) {
    __shared__ float wdT[C][32];
    __shared__ float wrT[C][32];
    int tid = threadIdx.x;
    for (int i = tid; i < 32 * C; i += 256) {
        int o = i / C, c = i - o * C;
        float wd = W[o * 2 * C + c];
        float wc = W[o * 2 * C + C + c];
        wdT[c][o] = wd;
        wrT[c][o] = wc - wd;
    }
    __syncthreads();
    int lane = tid & 63;
    int o = lane & 31;
    int h = lane >> 5;
    int wv = tid >> 6;
    int flat = blockIdx.x * 8 + wv * 2 + h;   // 2048 wgs * 8 points = B*N
    int b = flat >> 11, n = flat & 2047;
    const float* Xb = X + (long)b * bstride + n;
    float pacc = 0.f, racc = 0.f, xxa = 0.f, xto = 0.f;
    double xxd = 0.0;
#pragma unroll
    for (int c = 0; c < C; c++) {
        float xv = Xb[(long)c * NP];
        pacc = fmaf(wdT[c][o], xv, pacc);
        racc = fmaf(wrT[c][o], xv, racc);
        xxa += xv * xv;
        xxd += (double)xv * (double)xv;       // sequential c order (refine-consistent)
        if (c == o) xto = xv;
    }
    long base = ((long)b * NP + n) * 32 + o;
    p[base] = pacc;
    r[base] = racc;
    long rowb = ((long)b * NP + n) * CPX;
    if (o < CP) XT[rowb + o] = (o < C) ? xto : 0.f;
    if (o == 0) {
        xx[b * NP + n] = xxa;
        *reinterpret_cast<double*>(&XT[rowb + CP]) = xxd;
    }
}

// ---------------------------------------------------------------------------
// knn: per (b,n) row. Design rules (R2-R13, measured):
//  (1) register ARRAYS well under ~95: 2 rows/wave, 16 packed key regs/row
//      (4 rows spilled in R13); wave-uniform queries in LDS broadcast.
//  (2) pass-1 is LDS-BANDWIDTH/width-bound (b32=22 B/cyc vs b128=85):
//      stage TWO 128-tiles per barrier round; half-wave h computes on tile
//      2*t2+h; lane owns m = t2*256 + h*128 + 4*l32 + j -> the tile read is
//      ONE ds_read_b128 per c (R10 tile unit + staging kept; R11's 256-tile
//      structure stays retired).
//  select: 16-iter ballot bisection on 16-bit keys -> rank-40 bucket;
//  candidates {k16 <= rank40+2}; refine in float64 from point-contiguous XT;
//  64-bit bisect -> exact top-40; boundary ties lowest-index-first via
//  m-bisect. Defensive sel-init + index masking retained (R9).
// wg = 256 = 4 waves; each wave owns 2 rows; 2048 wgs (256 per batch).
// ---------------------------------------------------------------------------
template<int C, int CP, int CPX>
__global__ __launch_bounds__(256, 2)
void knn_kernel(const float* __restrict__ X, long bstride,
                const float* __restrict__ p, const float* __restrict__ r,
                const float* __restrict__ xx, const float* __restrict__ XT,
                float* __restrict__ mmax, float* __restrict__ mmin,
                float* __restrict__ sums) {
    __shared__ __align__(16) float xt[2][C * 128]; // two 128-tiles per round
    __shared__ __align__(16) float xxt[256];
    __shared__ __align__(8) float qld[4][CP][2];   // [wave][c][rowA/rowB]
    __shared__ int sel[8][KNN];
    __shared__ int cand[8][CAP];
    __shared__ float S1loc[32], S2loc[32];
    int tid = threadIdx.x;
    if (tid < 32) { S1loc[tid] = 0.f; S2loc[tid] = 0.f; }
    for (int i = tid; i < 8 * KNN; i += 256) ((int*)sel)[i] = 0;   // defensive init
    int lane = tid & 63;
    int wv = tid >> 6;
    int half = lane >> 5;                 // which of the 2 staged tiles
    int l32 = lane & 31;
    int b = blockIdx.x >> 8;              // 256 wgs per batch
    int n0 = (blockIdx.x & 255) * 8;
    int nA = n0 + wv * 2, nB = nA + 1;
    const float* Xb = X + (long)b * bstride;
    const float* XTb = XT + (long)b * NP * CPX;
    long bNP = (long)b * NP;

    // queries -> LDS (wave-private rows; barrier below covers visibility)
    if (lane < CP) {
        qld[wv][lane][0] = XTb[(long)nA * CPX + lane];
        qld[wv][lane][1] = XTb[(long)nB * CPX + lane];
    }
    float xxnA = xx[bNP + nA];
    float xxnB = xx[bNP + nB];

    unsigned uA[16], uB[16];   // 16-bit keys packed 2/reg; slot 2*t2+s, s=j>>1
    for (int t2 = 0; t2 < 8; t2++) {
        __syncthreads();
        // stage tiles 2*t2 (->xt[0]) and 2*t2+1 (->xt[1]); R10 staging pattern
        for (int i = tid; i < C * 64; i += 256) {
            int c = i >> 6, g = i & 63;
            int tt = g >> 5, gg = g & 31;
            *(float4*)&xt[tt][c * 128 + gg * 4] =
                *(const float4*)&Xb[(long)c * NP + (t2 * 2 + tt) * 128 + gg * 4];
        }
        xxt[tid] = xx[bNP + t2 * 256 + tid];
        __syncthreads();
        const float* xth = xt[half];
        float4 ia = make_float4(0.f, 0.f, 0.f, 0.f);
        float4 ib = make_float4(0.f, 0.f, 0.f, 0.f);
#pragma unroll
        for (int c = 0; c < C; c++) {
            float2 q = *(const float2*)&qld[wv][c][0];      // b64 broadcast
            float4 xv = *(const float4*)&xth[c * 128 + 4 * l32]; // ONE b128/c
            ia.x = fmaf(q.x, xv.x, ia.x);
            ia.y = fmaf(q.x, xv.y, ia.y);
            ia.z = fmaf(q.x, xv.z, ia.z);
            ia.w = fmaf(q.x, xv.w, ia.w);
            ib.x = fmaf(q.y, xv.x, ib.x);
            ib.y = fmaf(q.y, xv.y, ib.y);
            ib.z = fmaf(q.y, xv.z, ib.z);
            ib.w = fmaf(q.y, xv.w, ib.w);
        }
        float4 xm = *(const float4*)&xxt[half * 128 + 4 * l32];
        unsigned a0 = fOrd((xxnA - 2.0f * ia.x) + xm.x) >> 16;   // ref rounding
        unsigned a1 = fOrd((xxnA - 2.0f * ia.y) + xm.y) >> 16;
        unsigned a2 = fOrd((xxnA - 2.0f * ia.z) + xm.z) >> 16;
        unsigned a3 = fOrd((xxnA - 2.0f * ia.w) + xm.w) >> 16;
        unsigned b0 = fOrd((xxnB - 2.0f * ib.x) + xm.x) >> 16;
        unsigned b1 = fOrd((xxnB - 2.0f * ib.y) + xm.y) >> 16;
        unsigned b2_ = fOrd((xxnB - 2.0f * ib.z) + xm.z) >> 16;
        unsigned b3 = fOrd((xxnB - 2.0f * ib.w) + xm.w) >> 16;
        uA[2 * t2]     = (a1 << 16) | a0;
        uA[2 * t2 + 1] = (a3 << 16) | a2;
        uB[2 * t2]     = (b1 << 16) | b0;
        uB[2 * t2 + 1] = (b3 << 16) | b2_;
    }

    unsigned long long lmlt = (1ull << lane) - 1ull;
    auto do_row = [&](unsigned (&u)[16], int rsel, int row, int n) {
        // --- pass 1 select: rank-40 among 16-bit truncated keys ---
        unsigned lo = 0u, hi = 0xFFFFu;
        while (lo < hi) {
            unsigned mid = (lo + hi) >> 1;
            int cnt = 0;
#pragma unroll
            for (int t = 0; t < 16; t++) {
                cnt += __popcll(__ballot((u[t] & 0xFFFFu) <= mid));
                cnt += __popcll(__ballot((u[t] >> 16) <= mid));
            }
            if (cnt >= KNN) hi = mid; else lo = mid + 1;
        }
        unsigned thr = (lo > 0xFFFDu) ? 0xFFFFu : lo + 2;   // 2-bucket margin
        // --- candidate list (m = t2*256 + half*128 + 4*l32 + j) ---
        int base = 0;
#pragma unroll
        for (int kk = 0; kk < 16; kk++) {
#pragma unroll
            for (int hh = 0; hh < 2; hh++) {
                unsigned k16 = hh ? (u[kk] >> 16) : (u[kk] & 0xFFFFu);
                bool pr = (k16 <= thr);
                unsigned long long mk = __ballot(pr);
                if (pr) {
                    int pos = base + __popcll(mk & lmlt);
                    if (pos < CAP)
                        cand[row][pos] = (kk >> 1) * 256 + half * 128 + 4 * l32
                                       + (kk & 1) * 2 + hh;
                }
                base += __popcll(mk);
            }
        }
        int cnt = base < CAP ? base : CAP;
        // --- refine candidates in float64 (query via LDS broadcast) ---
        double xxdn = *reinterpret_cast<const double*>(&XTb[(long)n * CPX + CP]);
        unsigned long long key[CAP / 64]; int midx[CAP / 64];
#pragma unroll
        for (int s3 = 0; s3 < CAP / 64; s3++) {
            int slot = s3 * 64 + lane;
            key[s3] = ~0ull; midx[s3] = 0;
            if (slot < cnt) {
                int m = cand[row][slot] & (NP - 1);   // defensive mask
                midx[s3] = m;
                const float* xmp = XTb + (long)m * CPX;
                double inner = 0.0;
#pragma unroll
                for (int g = 0; g < CP / 4; g++) {
                    float4 v = *(const float4*)&xmp[g * 4];
                    inner += (double)qld[wv][g * 4 + 0][rsel] * (double)v.x;
                    inner += (double)qld[wv][g * 4 + 1][rsel] * (double)v.y;
                    inner += (double)qld[wv][g * 4 + 2][rsel] * (double)v.z;
                    inner += (double)qld[wv][g * 4 + 3][rsel] * (double)v.w;
                }
                double xxm = *reinterpret_cast<const double*>(&xmp[CP]);
                double dd = (xxdn - 2.0 * inner) + xxm;
                key[s3] = dOrd(dd);
            }
        }
        // --- 64-bit bisect for rank-40 among candidates ---
        unsigned long long lo64 = 0ull, hi64 = ~0ull;
        while (lo64 < hi64) {
            unsigned long long mid = lo64 + ((hi64 - lo64) >> 1);
            int c2 = 0;
#pragma unroll
            for (int s3 = 0; s3 < CAP / 64; s3++)
                c2 += __popcll(__ballot(key[s3] <= mid));
            if (c2 >= KNN) hi64 = mid; else lo64 = mid + 1;
        }
        // --- emit strictly-smaller ---
        int b2 = 0;
#pragma unroll
        for (int s3 = 0; s3 < CAP / 64; s3++) {
            bool pr = (key[s3] < lo64);
            unsigned long long mk = __ballot(pr);
            if (pr) {
                int pos = b2 + __popcll(mk & lmlt);
                if (pos < KNN) sel[row][pos] = midx[s3];
            }
            b2 += __popcll(mk);
        }
        // --- boundary ties: take the (KNN-b2) LOWEST m among tied keys ---
        {
            int need = KNN - b2;
            int mlo = 0, mhi = NP - 1;
            while (mlo < mhi) {
                int mm = (mlo + mhi) >> 1;
                int ct = 0;
#pragma unroll
                for (int s3 = 0; s3 < CAP / 64; s3++)
                    ct += __popcll(__ballot(key[s3] == lo64 && midx[s3] <= mm));
                if (ct >= need) mhi = mm; else mlo = mm + 1;
            }
#pragma unroll
            for (int s3 = 0; s3 < CAP / 64; s3++) {
                bool pr = (key[s3] == lo64 && midx[s3] <= mlo);
                unsigned long long mk = __ballot(pr);
                if (pr) {
                    int pos = b2 + __popcll(mk & lmlt);
                    if (pos < KNN) sel[row][pos] = midx[s3];
                }
                b2 += __popcll(mk);
            }
        }
        // --- fused gather-reduce over the selected 40: lane = (o, half) ---
        int o = lane & 31, h = lane >> 5;
        float s1 = 0.f, s2 = 0.f;
        float mx = -__builtin_inff(), mn = __builtin_inff();
        const float* pb = p + bNP * 32 + o;
        for (int k = h * 20; k < h * 20 + 20; k++) {
            int m = sel[row][k] & (NP - 1);           // defensive mask
            float pv = pb[(long)m * 32];
            s1 += pv;
            s2 = fmaf(pv, pv, s2);
            mx = fmaxf(mx, pv);
            mn = fminf(mn, pv);
        }
        s1 += __shfl_xor(s1, 32);
        s2 += __shfl_xor(s2, 32);
        mx = fmaxf(mx, __shfl_xor(mx, 32));
        mn = fminf(mn, __shfl_xor(mn, 32));
        if (h == 0) {
            long bse = (bNP + n) * 32 + o;
            float q = r[bse];
            mmax[bse] = mx + q;
            mmin[bse] = mn + q;
            atomicAdd(&S1loc[o], s1 + 40.f * q);
            atomicAdd(&S2loc[o], fmaf(2.f * q, s1, fmaf(40.f * q, q, s2)));
        }
    };
    do_row(uA, 0, wv * 2, nA);
    do_row(uB, 1, wv * 2 + 1, nB);
    __syncthreads();
    if (tid < 32) {
        atomicAdd(&sums[tid], S1loc[tid]);
        atomicAdd(&sums[32 + tid], S2loc[tid]);
    }
}

// ---------------------------------------------------------------------------
// finish: per-channel BN affine from global sums, monotone max/min trick,
// LeakyReLU, residual, write slice of cat into d_out [B][128][N]
// ---------------------------------------------------------------------------
__global__ void finish_kernel(const float* __restrict__ mmax, const float* __restrict__ mmin,
                              const float* __restrict__ sums,
                              const float* __restrict__ g, const float* __restrict__ be,
                              const float* __restrict__ resid,
                              float* __restrict__ outb) {
    int id = blockIdx.x * 256 + threadIdx.x;     // B*32*N = 524288
    int b = id >> 16;
    int o = (id >> 11) & 31;
    int n = id & 2047;
    const float cntf = 655360.0f;                 // B*N*K
    float mean = sums[o] / cntf;
    float var = sums[32 + o] / cntf - mean * mean;
    float sc = g[o] / sqrtf(var + 1e-5f);
    float sh = be[o] - mean * sc;
    long bse = ((long)b * NP + n) * 32 + o;
    float v = (sc >= 0.f) ? mmax[bse] : mmin[bse];
    float y = sc * v + sh;
    y = (y >= 0.f) ? y : 0.2f * y;
    long ob = ((long)b * 128 + o) * NP + n;
    if (resid) y += resid[ob];
    outb[ob] = y;
}

// ---------------------------------------------------------------------------
// final in-place GEMM on d_out: out[b,o,n] = sum_c W5[o,c]*cat[b,c,n]
// ---------------------------------------------------------------------------
__global__ void final_gemm(const float* __restrict__ W5, float* __restrict__ out) {
    __shared__ __align__(16) float catL[128][32];
    int b = blockIdx.x >> 6;
    int n0 = (blockIdx.x & 63) * 32;
    int tid = threadIdx.x;
    for (int i = tid; i < 128 * 32; i += 256) {
        int c = i >> 5, nn = i & 31;
        catL[c][nn] = out[((long)b * 128 + c) * NP + n0 + nn];
    }
    __syncthreads();
    int og = tid >> 3, ng = tid & 7;
    int o0 = og * 4, nl = ng * 4;
    float acc[4][4] = {};
    for (int c = 0; c < 128; c++) {
        float4 cv = *(const float4*)&catL[c][nl];
#pragma unroll
        for (int i = 0; i < 4; i++) {
            float w = W5[(o0 + i) * 128 + c];
            acc[i][0] = fmaf(w, cv.x, acc[i][0]);
            acc[i][1] = fmaf(w, cv.y, acc[i][1]);
            acc[i][2] = fmaf(w, cv.z, acc[i][2]);
            acc[i][3] = fmaf(w, cv.w, acc[i][3]);
        }
    }
#pragma unroll
    for (int i = 0; i < 4; i++) {
        float4 vv = make_float4(acc[i][0], acc[i][1], acc[i][2], acc[i][3]);
        *(float4*)&out[((long)b * 128 + o0 + i) * NP + n0 + nl] = vv;
    }
}

extern "C" void kernel_launch(void* const* d_in, const int* in_sizes, int n_in,
                              void* d_out, int out_size, void* d_ws, size_t ws_size,
                              hipStream_t stream) {
    const float* x  = (const float*)d_in[0];
    const float* W1 = (const float*)d_in[1];
    const float* W2 = (const float*)d_in[2];
    const float* W3 = (const float*)d_in[3];
    const float* W4 = (const float*)d_in[4];
    const float* W5 = (const float*)d_in[5];
    const float* g1 = (const float*)d_in[6];
    const float* b1 = (const float*)d_in[7];
    const float* g2 = (const float*)d_in[8];
    const float* b2 = (const float*)d_in[9];
    const float* g3 = (const float*)d_in[10];
    const float* b3 = (const float*)d_in[11];
    const float* g4 = (const float*)d_in[12];
    const float* b4 = (const float*)d_in[13];
    float* out = (float*)d_out;
    float* ws  = (float*)d_ws;
    // ws layout (floats): p | r | mmax | mmin | xx | sums | XT
    float* p    = ws;
    float* r    = ws + 524288;
    float* mmax = ws + 1048576;
    float* mmin = ws + 1572864;
    float* xx   = ws + 2097152;
    float* sums = ws + 2113536;
    float* XT   = ws + 2113792;   // up to 8*2048*36 = 589824 floats
    hipMemsetAsync(sums, 0, 256 * sizeof(float), stream);

    // block 1 (C=9, CP=12, CPX=16)
    prep_kernel<9, 12, 16><<<2048, 256, 0, stream>>>(x, 9L * NP, W1, p, r, xx, XT);
    knn_kernel<9, 12, 16><<<2048, 256, 0, stream>>>(x, 9L * NP, p, r, xx, XT, mmax, mmin, sums);
    finish_kernel<<<2048, 256, 0, stream>>>(mmax, mmin, sums, g1, b1, nullptr, out);
    // block 2 (C=32, CP=32, CPX=36)
    const float* x1 = out;
    prep_kernel<32, 32, 36><<<2048, 256, 0, stream>>>(x1, 128L * NP, W2, p, r, xx, XT);
    knn_kernel<32, 32, 36><<<2048, 256, 0, stream>>>(x1, 128L * NP, p, r, xx, XT, mmax, mmin, sums + 64);
    finish_kernel<<<2048, 256, 0, stream>>>(mmax, mmin, sums + 64, g2, b2, x1, out + 32 * NP);
    // block 3
    const float* x2 = out + 32 * NP;
    prep_kernel<32, 32, 36><<<2048, 256, 0, stream>>>(x2, 128L * NP, W3, p, r, xx, XT);
    knn_kernel<32, 32, 36><<<2048, 256, 0, stream>>>(x2, 128L * NP, p, r, xx, XT, mmax, mmin, sums + 128);
    finish_kernel<<<2048, 256, 0, stream>>>(mmax, mmin, sums + 128, g3, b3, x2, out + 64 * NP);
    // block 4
    const float* x3 = out + 64 * NP;
    prep_kernel<32, 32, 36><<<2048, 256, 0, stream>>>(x3, 128L * NP, W4, p, r, xx, XT);
    knn_kernel<32, 32, 36><<<2048, 256, 0, stream>>>(x3, 128L * NP, p, r, xx, XT, mmax, mmin, sums + 192);
    finish_kernel<<<2048, 256, 0, stream>>>(mmax, mmin, sums + 192, g4, b4, x3, out + 96 * NP);

    final_gemm<<<512, 256, 0, stream>>>(W5, out);
}

// Round 17
// 786.477 us; speedup vs baseline: 1.6143x; 1.1133x over previous
//
#include <hip/hip_runtime.h>
#include <stdint.h>

#define NP 2048
#define KNN 40
#define CAP 128          // candidate buffer per row (2 slots of 64, int — proven type)

__device__ __forceinline__ unsigned fOrd(float f) {
    unsigned u = __float_as_uint(f);
    return u ^ ((unsigned)((int)u >> 31) | 0x80000000u);
}
__device__ __forceinline__ unsigned long long dOrd(double d) {
    unsigned long long u = (unsigned long long)__double_as_longlong(d);
    return u ^ (((unsigned long long)((long long)u >> 63)) | 0x8000000000000000ull);
}

// ---------------------------------------------------------------------------
// prep: per point: xx = sum x^2 (fp32), p[o] = Wd[o,:]·x, r[o] = (Wc-Wd)[o,:]·x,
// XT[b][n][0..CP) = x (point-contiguous, zero-padded) + fp64 norm at offset CP
// (sequential c-order — must match refine's usage).
// ---------------------------------------------------------------------------
template<int C, int CP, int CPX>
__global__ void prep_kernel(const float* __restrict__ X, long bstride,
                            const float* __restrict__ W,
                            float* __restrict__ p, float* __restrict__ r,
                            float* __restrict__ xx, float* __restrict__ XT) {
    __shared__ float wdT[C][32];
    __shared__ float wrT[C][32];
    int tid = threadIdx.x;
    for (int i = tid; i < 32 * C; i += 256) {
        int o = i / C, c = i - o * C;
        float wd = W[o * 2 * C + c];
        float wc = W[o * 2 * C + C + c];
        wdT[c][o] = wd;
        wrT[c][o] = wc - wd;
    }
    __syncthreads();
    int lane = tid & 63;
    int o = lane & 31;
    int h = lane >> 5;
    int wv = tid >> 6;
    int flat = blockIdx.x * 8 + wv * 2 + h;   // 2048 wgs * 8 points = B*N
    int b = flat >> 11, n = flat & 2047;
    const float* Xb = X + (long)b * bstride + n;
    float pacc = 0.f, racc = 0.f, xxa = 0.f, xto = 0.f;
    double xxd = 0.0;
#pragma unroll
    for (int c = 0; c < C; c++) {
        float xv = Xb[(long)c * NP];
        pacc = fmaf(wdT[c][o], xv, pacc);
        racc = fmaf(wrT[c][o], xv, racc);
        xxa += xv * xv;
        xxd += (double)xv * (double)xv;       // sequential c order (refine-consistent)
        if (c == o) xto = xv;
    }
    long base = ((long)b * NP + n) * 32 + o;
    p[base] = pacc;
    r[base] = racc;
    long rowb = ((long)b * NP + n) * CPX;
    if (o < CP) XT[rowb + o] = (o < C) ? xto : 0.f;
    if (o == 0) {
        xx[b * NP + n] = xxa;
        *reinterpret_cast<double*>(&XT[rowb + CP]) = xxd;
    }
}

// ---------------------------------------------------------------------------
// knn: per (b,n) row. Design rules (R2-R16, measured):
//  (1) register ARRAYS well under ~95: 2 rows/wave, 16 packed key regs/row.
//  (2) pass-1 b128 tile reads (two 128-tiles per round, half-wave split) —
//      R14-proven structure, byte-identical here.
//  (3) occupancy: CAP=128 int cand -> LDS ~40.4 KB -> 4 blocks/CU.
//  (4) margin +1 bucket (proven): fp32 pipeline error ~2^7 ulps << one
//      16-bit bucket (2^16 ulps) -> true top-40 has k16 <= b40+1.
//  (5) R15/R16 constructs (ushort LDS arrays, NSLOT=3, tie shortcut)
//      RETIRED — they core-dump; only int arrays + full m-bisect here.
//  select: 16-iter ballot bisection on 16-bit keys; candidates {k16<=b40+1};
//  refine in float64 from point-contiguous XT; 64-bit bisect -> exact top-40;
//  boundary ties lowest-index-first via m-bisect. Defensive sel-init +
//  index masking retained (R9).
// wg = 256 = 4 waves; each wave owns 2 rows; 2048 wgs (256 per batch).
// ---------------------------------------------------------------------------
template<int C, int CP, int CPX>
__global__ __launch_bounds__(256, 2)
void knn_kernel(const float* __restrict__ X, long bstride,
                const float* __restrict__ p, const float* __restrict__ r,
                const float* __restrict__ xx, const float* __restrict__ XT,
                float* __restrict__ mmax, float* __restrict__ mmin,
                float* __restrict__ sums) {
    __shared__ __align__(16) float xt[2][C * 128]; // two 128-tiles per round
    __shared__ __align__(16) float xxt[256];
    __shared__ __align__(8) float qld[4][CP][2];   // [wave][c][rowA/rowB]
    __shared__ int sel[8][KNN];
    __shared__ int cand[8][CAP];
    __shared__ float S1loc[32], S2loc[32];
    int tid = threadIdx.x;
    if (tid < 32) { S1loc[tid] = 0.f; S2loc[tid] = 0.f; }
    for (int i = tid; i < 8 * KNN; i += 256) ((int*)sel)[i] = 0;   // defensive init
    int lane = tid & 63;
    int wv = tid >> 6;
    int half = lane >> 5;                 // which of the 2 staged tiles
    int l32 = lane & 31;
    int b = blockIdx.x >> 8;              // 256 wgs per batch
    int n0 = (blockIdx.x & 255) * 8;
    int nA = n0 + wv * 2, nB = nA + 1;
    const float* Xb = X + (long)b * bstride;
    const float* XTb = XT + (long)b * NP * CPX;
    long bNP = (long)b * NP;

    // queries -> LDS (wave-private rows; barrier below covers visibility)
    if (lane < CP) {
        qld[wv][lane][0] = XTb[(long)nA * CPX + lane];
        qld[wv][lane][1] = XTb[(long)nB * CPX + lane];
    }
    float xxnA = xx[bNP + nA];
    float xxnB = xx[bNP + nB];

    unsigned uA[16], uB[16];   // 16-bit keys packed 2/reg; slot 2*t2+s, s=j>>1
    for (int t2 = 0; t2 < 8; t2++) {
        __syncthreads();
        // stage tiles 2*t2 (->xt[0]) and 2*t2+1 (->xt[1]); R10 staging pattern
        for (int i = tid; i < C * 64; i += 256) {
            int c = i >> 6, g = i & 63;
            int tt = g >> 5, gg = g & 31;
            *(float4*)&xt[tt][c * 128 + gg * 4] =
                *(const float4*)&Xb[(long)c * NP + (t2 * 2 + tt) * 128 + gg * 4];
        }
        xxt[tid] = xx[bNP + t2 * 256 + tid];
        __syncthreads();
        const float* xth = xt[half];
        float4 ia = make_float4(0.f, 0.f, 0.f, 0.f);
        float4 ib = make_float4(0.f, 0.f, 0.f, 0.f);
#pragma unroll
        for (int c = 0; c < C; c++) {
            float2 q = *(const float2*)&qld[wv][c][0];      // b64 broadcast
            float4 xv = *(const float4*)&xth[c * 128 + 4 * l32]; // ONE b128/c
            ia.x = fmaf(q.x, xv.x, ia.x);
            ia.y = fmaf(q.x, xv.y, ia.y);
            ia.z = fmaf(q.x, xv.z, ia.z);
            ia.w = fmaf(q.x, xv.w, ia.w);
            ib.x = fmaf(q.y, xv.x, ib.x);
            ib.y = fmaf(q.y, xv.y, ib.y);
            ib.z = fmaf(q.y, xv.z, ib.z);
            ib.w = fmaf(q.y, xv.w, ib.w);
        }
        float4 xm = *(const float4*)&xxt[half * 128 + 4 * l32];
        unsigned a0 = fOrd((xxnA - 2.0f * ia.x) + xm.x) >> 16;   // ref rounding
        unsigned a1 = fOrd((xxnA - 2.0f * ia.y) + xm.y) >> 16;
        unsigned a2 = fOrd((xxnA - 2.0f * ia.z) + xm.z) >> 16;
        unsigned a3 = fOrd((xxnA - 2.0f * ia.w) + xm.w) >> 16;
        unsigned b0 = fOrd((xxnB - 2.0f * ib.x) + xm.x) >> 16;
        unsigned b1 = fOrd((xxnB - 2.0f * ib.y) + xm.y) >> 16;
        unsigned b2_ = fOrd((xxnB - 2.0f * ib.z) + xm.z) >> 16;
        unsigned b3 = fOrd((xxnB - 2.0f * ib.w) + xm.w) >> 16;
        uA[2 * t2]     = (a1 << 16) | a0;
        uA[2 * t2 + 1] = (a3 << 16) | a2;
        uB[2 * t2]     = (b1 << 16) | b0;
        uB[2 * t2 + 1] = (b3 << 16) | b2_;
    }

    unsigned long long lmlt = (1ull << lane) - 1ull;
    auto do_row = [&](unsigned (&u)[16], int rsel, int row, int n) {
        // --- pass 1 select: rank-40 among 16-bit truncated keys ---
        unsigned lo = 0u, hi = 0xFFFFu;
        while (lo < hi) {
            unsigned mid = (lo + hi) >> 1;
            int cnt = 0;
#pragma unroll
            for (int t = 0; t < 16; t++) {
                cnt += __popcll(__ballot((u[t] & 0xFFFFu) <= mid));
                cnt += __popcll(__ballot((u[t] >> 16) <= mid));
            }
            if (cnt >= KNN) hi = mid; else lo = mid + 1;
        }
        unsigned thr = (lo > 0xFFFEu) ? 0xFFFFu : lo + 1;   // +1 bucket (proven)
        // --- candidate list (m = t2*256 + half*128 + 4*l32 + j) ---
        int base = 0;
#pragma unroll
        for (int kk = 0; kk < 16; kk++) {
#pragma unroll
            for (int hh = 0; hh < 2; hh++) {
                unsigned k16 = hh ? (u[kk] >> 16) : (u[kk] & 0xFFFFu);
                bool pr = (k16 <= thr);
                unsigned long long mk = __ballot(pr);
                if (pr) {
                    int pos = base + __popcll(mk & lmlt);
                    if (pos < CAP)
                        cand[row][pos] = (kk >> 1) * 256 + half * 128 + 4 * l32
                                       + (kk & 1) * 2 + hh;
                }
                base += __popcll(mk);
            }
        }
        int cnt = base < CAP ? base : CAP;
        // --- refine candidates in float64 (query via LDS broadcast) ---
        double xxdn = *reinterpret_cast<const double*>(&XTb[(long)n * CPX + CP]);
        unsigned long long key[CAP / 64]; int midx[CAP / 64];
#pragma unroll
        for (int s3 = 0; s3 < CAP / 64; s3++) {
            int slot = s3 * 64 + lane;
            key[s3] = ~0ull; midx[s3] = 0;
            if (slot < cnt) {
                int m = cand[row][slot] & (NP - 1);   // defensive mask
                midx[s3] = m;
                const float* xmp = XTb + (long)m * CPX;
                double inner = 0.0;
#pragma unroll
                for (int g = 0; g < CP / 4; g++) {
                    float4 v = *(const float4*)&xmp[g * 4];
                    inner += (double)qld[wv][g * 4 + 0][rsel] * (double)v.x;
                    inner += (double)qld[wv][g * 4 + 1][rsel] * (double)v.y;
                    inner += (double)qld[wv][g * 4 + 2][rsel] * (double)v.z;
                    inner += (double)qld[wv][g * 4 + 3][rsel] * (double)v.w;
                }
                double xxm = *reinterpret_cast<const double*>(&xmp[CP]);
                double dd = (xxdn - 2.0 * inner) + xxm;
                key[s3] = dOrd(dd);
            }
        }
        // --- 64-bit bisect for rank-40 among candidates ---
        unsigned long long lo64 = 0ull, hi64 = ~0ull;
        while (lo64 < hi64) {
            unsigned long long mid = lo64 + ((hi64 - lo64) >> 1);
            int c2 = 0;
#pragma unroll
            for (int s3 = 0; s3 < CAP / 64; s3++)
                c2 += __popcll(__ballot(key[s3] <= mid));
            if (c2 >= KNN) hi64 = mid; else lo64 = mid + 1;
        }
        // --- emit strictly-smaller ---
        int b2 = 0;
#pragma unroll
        for (int s3 = 0; s3 < CAP / 64; s3++) {
            bool pr = (key[s3] < lo64);
            unsigned long long mk = __ballot(pr);
            if (pr) {
                int pos = b2 + __popcll(mk & lmlt);
                if (pos < KNN) sel[row][pos] = midx[s3];
            }
            b2 += __popcll(mk);
        }
        // --- boundary ties: take the (KNN-b2) LOWEST m among tied keys ---
        {
            int need = KNN - b2;
            int mlo = 0, mhi = NP - 1;
            while (mlo < mhi) {
                int mm = (mlo + mhi) >> 1;
                int ct = 0;
#pragma unroll
                for (int s3 = 0; s3 < CAP / 64; s3++)
                    ct += __popcll(__ballot(key[s3] == lo64 && midx[s3] <= mm));
                if (ct >= need) mhi = mm; else mlo = mm + 1;
            }
#pragma unroll
            for (int s3 = 0; s3 < CAP / 64; s3++) {
                bool pr = (key[s3] == lo64 && midx[s3] <= mlo);
                unsigned long long mk = __ballot(pr);
                if (pr) {
                    int pos = b2 + __popcll(mk & lmlt);
                    if (pos < KNN) sel[row][pos] = midx[s3];
                }
                b2 += __popcll(mk);
            }
        }
        // --- fused gather-reduce over the selected 40: lane = (o, half) ---
        int o = lane & 31, h = lane >> 5;
        float s1 = 0.f, s2 = 0.f;
        float mx = -__builtin_inff(), mn = __builtin_inff();
        const float* pb = p + bNP * 32 + o;
        for (int k = h * 20; k < h * 20 + 20; k++) {
            int m = sel[row][k] & (NP - 1);           // defensive mask
            float pv = pb[(long)m * 32];
            s1 += pv;
            s2 = fmaf(pv, pv, s2);
            mx = fmaxf(mx, pv);
            mn = fminf(mn, pv);
        }
        s1 += __shfl_xor(s1, 32);
        s2 += __shfl_xor(s2, 32);
        mx = fmaxf(mx, __shfl_xor(mx, 32));
        mn = fminf(mn, __shfl_xor(mn, 32));
        if (h == 0) {
            long bse = (bNP + n) * 32 + o;
            float q = r[bse];
            mmax[bse] = mx + q;
            mmin[bse] = mn + q;
            atomicAdd(&S1loc[o], s1 + 40.f * q);
            atomicAdd(&S2loc[o], fmaf(2.f * q, s1, fmaf(40.f * q, q, s2)));
        }
    };
    do_row(uA, 0, wv * 2, nA);
    do_row(uB, 1, wv * 2 + 1, nB);
    __syncthreads();
    if (tid < 32) {
        atomicAdd(&sums[tid], S1loc[tid]);
        atomicAdd(&sums[32 + tid], S2loc[tid]);
    }
}

// ---------------------------------------------------------------------------
// finish: per-channel BN affine from global sums, monotone max/min trick,
// LeakyReLU, residual, write slice of cat into d_out [B][128][N]
// ---------------------------------------------------------------------------
__global__ void finish_kernel(const float* __restrict__ mmax, const float* __restrict__ mmin,
                              const float* __restrict__ sums,
                              const float* __restrict__ g, const float* __restrict__ be,
                              const float* __restrict__ resid,
                              float* __restrict__ outb) {
    int id = blockIdx.x * 256 + threadIdx.x;     // B*32*N = 524288
    int b = id >> 16;
    int o = (id >> 11) & 31;
    int n = id & 2047;
    const float cntf = 655360.0f;                 // B*N*K
    float mean = sums[o] / cntf;
    float var = sums[32 + o] / cntf - mean * mean;
    float sc = g[o] / sqrtf(var + 1e-5f);
    float sh = be[o] - mean * sc;
    long bse = ((long)b * NP + n) * 32 + o;
    float v = (sc >= 0.f) ? mmax[bse] : mmin[bse];
    float y = sc * v + sh;
    y = (y >= 0.f) ? y : 0.2f * y;
    long ob = ((long)b * 128 + o) * NP + n;
    if (resid) y += resid[ob];
    outb[ob] = y;
}

// ---------------------------------------------------------------------------
// final in-place GEMM on d_out: out[b,o,n] = sum_c W5[o,c]*cat[b,c,n]
// ---------------------------------------------------------------------------
__global__ void final_gemm(const float* __restrict__ W5, float* __restrict__ out) {
    __shared__ __align__(16) float catL[128][32];
    int b = blockIdx.x >> 6;
    int n0 = (blockIdx.x & 63) * 32;
    int tid = threadIdx.x;
    for (int i = tid; i < 128 * 32; i += 256) {
        int c = i >> 5, nn = i & 31;
        catL[c][nn] = out[((long)b * 128 + c) * NP + n0 + nn];
    }
    __syncthreads();
    int og = tid >> 3, ng = tid & 7;
    int o0 = og * 4, nl = ng * 4;
    float acc[4][4] = {};
    for (int c = 0; c < 128; c++) {
        float4 cv = *(const float4*)&catL[c][nl];
#pragma unroll
        for (int i = 0; i < 4; i++) {
            float w = W5[(o0 + i) * 128 + c];
            acc[i][0] = fmaf(w, cv.x, acc[i][0]);
            acc[i][1] = fmaf(w, cv.y, acc[i][1]);
            acc[i][2] = fmaf(w, cv.z, acc[i][2]);
            acc[i][3] = fmaf(w, cv.w, acc[i][3]);
        }
    }
#pragma unroll
    for (int i = 0; i < 4; i++) {
        float4 vv = make_float4(acc[i][0], acc[i][1], acc[i][2], acc[i][3]);
        *(float4*)&out[((long)b * 128 + o0 + i) * NP + n0 + nl] = vv;
    }
}

extern "C" void kernel_launch(void* const* d_in, const int* in_sizes, int n_in,
                              void* d_out, int out_size, void* d_ws, size_t ws_size,
                              hipStream_t stream) {
    const float* x  = (const float*)d_in[0];
    const float* W1 = (const float*)d_in[1];
    const float* W2 = (const float*)d_in[2];
    const float* W3 = (const float*)d_in[3];
    const float* W4 = (const float*)d_in[4];
    const float* W5 = (const float*)d_in[5];
    const float* g1 = (const float*)d_in[6];
    const float* b1 = (const float*)d_in[7];
    const float* g2 = (const float*)d_in[8];
    const float* b2 = (const float*)d_in[9];
    const float* g3 = (const float*)d_in[10];
    const float* b3 = (const float*)d_in[11];
    const float* g4 = (const float*)d_in[12];
    const float* b4 = (const float*)d_in[13];
    float* out = (float*)d_out;
    float* ws  = (float*)d_ws;
    // ws layout (floats): p | r | mmax | mmin | xx | sums | XT
    float* p    = ws;
    float* r    = ws + 524288;
    float* mmax = ws + 1048576;
    float* mmin = ws + 1572864;
    float* xx   = ws + 2097152;
    float* sums = ws + 2113536;
    float* XT   = ws + 2113792;   // up to 8*2048*36 = 589824 floats
    hipMemsetAsync(sums, 0, 256 * sizeof(float), stream);

    // block 1 (C=9, CP=12, CPX=16)
    prep_kernel<9, 12, 16><<<2048, 256, 0, stream>>>(x, 9L * NP, W1, p, r, xx, XT);
    knn_kernel<9, 12, 16><<<2048, 256, 0, stream>>>(x, 9L * NP, p, r, xx, XT, mmax, mmin, sums);
    finish_kernel<<<2048, 256, 0, stream>>>(mmax, mmin, sums, g1, b1, nullptr, out);
    // block 2 (C=32, CP=32, CPX=36)
    const float* x1 = out;
    prep_kernel<32, 32, 36><<<2048, 256, 0, stream>>>(x1, 128L * NP, W2, p, r, xx, XT);
    knn_kernel<32, 32, 36><<<2048, 256, 0, stream>>>(x1, 128L * NP, p, r, xx, XT, mmax, mmin, sums + 64);
    finish_kernel<<<2048, 256, 0, stream>>>(mmax, mmin, sums + 64, g2, b2, x1, out + 32 * NP);
    // block 3
    const float* x2 = out + 32 * NP;
    prep_kernel<32, 32, 36><<<2048, 256, 0, stream>>>(x2, 128L * NP, W3, p, r, xx, XT);
    knn_kernel<32, 32, 36><<<2048, 256, 0, stream>>>(x2, 128L * NP, p, r, xx, XT, mmax, mmin, sums + 128);
    finish_kernel<<<2048, 256, 0, stream>>>(mmax, mmin, sums + 128, g3, b3, x2, out + 64 * NP);
    // block 4
    const float* x3 = out + 64 * NP;
    prep_kernel<32, 32, 36><<<2048, 256, 0, stream>>>(x3, 128L * NP, W4, p, r, xx, XT);
    knn_kernel<32, 32, 36><<<2048, 256, 0, stream>>>(x3, 128L * NP, p, r, xx, XT, mmax, mmin, sums + 192);
    finish_kernel<<<2048, 256, 0, stream>>>(mmax, mmin, sums + 192, g4, b4, x3, out + 96 * NP);

    final_gemm<<<512, 256, 0, stream>>>(W5, out);
}